// Round 8
// baseline (1833.315 us; speedup 1.0000x reference)
//
#include <hip/hip_runtime.h>

#define NEG_SLOPE 0.01f
typedef unsigned short ushort_t;

#define CHUNK 32768       // edges per histogram/reorder block
#define BSHIFT 8          // 256 nodes per dst-bucket
#define BSZ 256           // nodes per bucket

static __device__ __forceinline__ float bf2f(ushort_t u) {
    return __uint_as_float(((unsigned int)u) << 16);
}
static __device__ __forceinline__ ushort_t f2bf(float f) {
    unsigned int x = __float_as_uint(f);
    x += 0x7fffu + ((x >> 16) & 1u);   // round-to-nearest-even
    return (ushort_t)(x >> 16);
}
static __device__ __forceinline__ float bcastf(float v, int lane) {
    return __int_as_float(__builtin_amdgcn_readlane(__float_as_int(v), lane));
}

// ---------------------------------------------------------------------------
// phase A: per-chunk dst-bucket histogram (LDS only) + zero xws sentinel row
// ---------------------------------------------------------------------------
__global__ __launch_bounds__(1024) void hist_kernel(const int* __restrict__ dst,
                                                    int* __restrict__ m,
                                                    ushort_t* __restrict__ xws,
                                                    int e, int nbk, int nch, int n) {
    __shared__ int lcnt[512];
    int t = threadIdx.x;
    if (t < 512) lcnt[t] = 0;
    __syncthreads();
    int base = blockIdx.x * CHUNK;
    int lim  = e - base; if (lim > CHUNK) lim = CHUNK;
    for (int j = t; j < lim; j += 1024)
        atomicAdd(&lcnt[dst[base + j] >> BSHIFT], 1);
    __syncthreads();
    if (t < nbk) m[t * nch + blockIdx.x] = lcnt[t];   // bucket-major
    if (blockIdx.x == 0 && t < 64) xws[(size_t)n * 64 + t] = 0;  // sentinel row
}

// exclusive scan of m[0..M) in place (single block, 16/thread, M<=16384)
__global__ __launch_bounds__(1024) void scanm_kernel(int* __restrict__ m, int M) {
    __shared__ int ts[1024];
    int t = threadIdx.x;
    int v[16], p[16];
    int s = 0;
    #pragma unroll
    for (int j = 0; j < 16; ++j) {
        int idx = t * 16 + j;
        v[j] = (idx < M) ? m[idx] : 0;
        s += v[j];
        p[j] = s;
    }
    ts[t] = s;
    __syncthreads();
    for (int st = 1; st < 1024; st <<= 1) {
        int x = (t >= st) ? ts[t - st] : 0;
        __syncthreads();
        ts[t] += x;
        __syncthreads();
    }
    int texcl = (t == 0) ? 0 : ts[t - 1];
    #pragma unroll
    for (int j = 0; j < 16; ++j) {
        int idx = t * 16 + j;
        if (idx < M) m[idx] = texcl + p[j] - v[j];
    }
}

// phase B: reorder edges into bucket-grouped ebuf; packed u32 = src | dloc<<24
__global__ __launch_bounds__(1024) void reorder_kernel(const int* __restrict__ src,
                                                       const int* __restrict__ dst,
                                                       const int* __restrict__ m,
                                                       unsigned* __restrict__ ebuf,
                                                       int e, int nbk, int nch) {
    __shared__ int cur[512];
    int t = threadIdx.x;
    if (t < nbk) cur[t] = m[t * nch + blockIdx.x];
    __syncthreads();
    int base = blockIdx.x * CHUNK;
    int lim  = e - base; if (lim > CHUNK) lim = CHUNK;
    for (int j = t; j < lim; j += 1024) {
        int i = base + j;
        int d = dst[i];
        int pos = atomicAdd(&cur[d >> BSHIFT], 1);
        ebuf[pos] = (unsigned)src[i] | ((unsigned)(d & (BSZ - 1)) << 24);
    }
}

// phase C: per-bucket degree count (LDS) -> dinv
__global__ __launch_bounds__(1024) void bucket_deg_kernel(const unsigned* __restrict__ ebuf,
                                                          const int* __restrict__ m,
                                                          float* __restrict__ dinv,
                                                          int e, int nbk, int nch, int n) {
    __shared__ int lc[BSZ];
    int t = threadIdx.x;
    int b = blockIdx.x;
    if (t < BSZ) lc[t] = 0;
    __syncthreads();
    int bs = m[b * nch];
    int be = (b + 1 < nbk) ? m[(b + 1) * nch] : e;
    for (int i = bs + t; i < be; i += 1024)
        atomicAdd(&lc[ebuf[i] >> 24], 1);
    __syncthreads();
    int v = (b << BSHIFT) + t;
    if (t < BSZ && v < n) dinv[v] = rsqrtf((float)lc[t] + 1.0f);
}

// ---------------------------------------------------------------------------
// xws = (Xc @ W) * dinv[row]  (bf16 out). W column in lane VGPRs; X rows
// broadcast via readlane. XF32=1: f32 input (layer 0); else bf16 Xcur.
// ---------------------------------------------------------------------------
template<int XF32>
__global__ __launch_bounds__(256) void gemm_rl(const float* __restrict__ Xf,
                                               const ushort_t* __restrict__ Xh,
                                               const float* __restrict__ W,
                                               const float* __restrict__ dinv,
                                               ushort_t* __restrict__ xws, int n) {
    int lane = threadIdx.x & 63;
    int wv   = threadIdx.x >> 6;

    float Wreg[64];
    #pragma unroll
    for (int k = 0; k < 64; ++k) Wreg[k] = W[k * 64 + lane];

    int row0 = blockIdx.x * 64 + wv * 16;
    int lr = lane >> 4;   // which of 4 rows this lane helps load
    int lc = lane & 15;   // 4-elem slot within row

    #pragma unroll 1
    for (int it = 0; it < 4; ++it) {
        int r = row0 + it * 4;
        float xr[4] = {0.f, 0.f, 0.f, 0.f};
        if (r + lr < n) {
            if (XF32) {
                float4 xv = *(const float4*)(Xf + (size_t)(r + lr) * 64 + lc * 4);
                xr[0] = xv.x; xr[1] = xv.y; xr[2] = xv.z; xr[3] = xv.w;
            } else {
                uint2 q = *(const uint2*)(Xh + (size_t)(r + lr) * 64 + lc * 4);
                xr[0] = bf2f((ushort_t)(q.x & 0xFFFF));
                xr[1] = bf2f((ushort_t)(q.x >> 16));
                xr[2] = bf2f((ushort_t)(q.y & 0xFFFF));
                xr[3] = bf2f((ushort_t)(q.y >> 16));
            }
        }
        float a0 = 0.f, a1 = 0.f, a2 = 0.f, a3 = 0.f;
        #pragma unroll
        for (int k = 0; k < 64; ++k) {
            float w = Wreg[k];
            a0 = fmaf(bcastf(xr[k & 3],      (k >> 2)), w, a0);
            a1 = fmaf(bcastf(xr[k & 3], 16 + (k >> 2)), w, a1);
            a2 = fmaf(bcastf(xr[k & 3], 32 + (k >> 2)), w, a2);
            a3 = fmaf(bcastf(xr[k & 3], 48 + (k >> 2)), w, a3);
        }
        if (r + 0 < n) xws[(size_t)(r + 0) * 64 + lane] = f2bf(a0 * dinv[r + 0]);
        if (r + 1 < n) xws[(size_t)(r + 1) * 64 + lane] = f2bf(a1 * dinv[r + 1]);
        if (r + 2 < n) xws[(size_t)(r + 2) * 64 + lane] = f2bf(a2 * dinv[r + 2]);
        if (r + 3 < n) xws[(size_t)(r + 3) * 64 + lane] = f2bf(a3 * dinv[r + 3]);
    }
}

// ---------------------------------------------------------------------------
// LDS-accumulator aggregation: one block per bucket (256 nodes), acc in LDS.
// Edge stream is uniform across 16 waves (zero divergence); gathers are
// 8-deep pipelined; ds_add_f32 at bank c&31 (2-way, free). Epilogue fuses
// bias + self + leakyReLU + residual + running sum, all coalesced.
// ---------------------------------------------------------------------------
template<int XF32>
__global__ __launch_bounds__(1024, 8) void agg_lds_kernel(
        const ushort_t* __restrict__ xws,
        const unsigned* __restrict__ ebuf,
        const int* __restrict__ m,
        const float* __restrict__ dinv,
        const float* __restrict__ bias,
        const float* __restrict__ xinf,    // f32 input (layer 0)
        const ushort_t* __restrict__ xinh, // bf16 Xcur (layers >0)
        ushort_t* __restrict__ xout,
        const float* __restrict__ rin,
        float* __restrict__ rout,
        float scale, int e, int nbk, int nch, int n) {
    __shared__ float acc[BSZ * 64];
    int t = threadIdx.x;
    int b = blockIdx.x;
    #pragma unroll
    for (int k = 0; k < 16; ++k) acc[t + 1024 * k] = 0.f;
    __syncthreads();

    int bs = m[b * nch];
    int be = (b + 1 < nbk) ? m[(b + 1) * nch] : e;
    int c  = t & 63;
    int w  = t >> 6;        // wave 0..15
    int l8 = c & 7;

    for (int i = bs + w * 8; i < be; i += 16 * 8) {
        int idx = i + l8;
        unsigned ed = (idx < be) ? ebuf[idx] : (unsigned)n;  // sentinel: src=n,dl=0
        float g[8]; int dl[8];
        #pragma unroll
        for (int j = 0; j < 8; ++j) {
            unsigned ev = (unsigned)__builtin_amdgcn_readlane((int)ed, j);
            int s = (int)(ev & 0xFFFFFFu);
            dl[j] = (int)(ev >> 24);
            g[j]  = bf2f(xws[(size_t)s * 64 + c]);
        }
        #pragma unroll
        for (int j = 0; j < 8; ++j)
            atomicAdd(&acc[dl[j] * 64 + c], g[j]);
    }
    __syncthreads();

    int vbase = b << BSHIFT;
    #pragma unroll
    for (int k = 0; k < 16; ++k) {
        int idx = t + 1024 * k;
        int vl  = idx >> 6;
        int v   = vbase + vl;
        if (v < n) {
            int cc = idx & 63;
            size_t vo = (size_t)v * 64 + cc;
            float dv  = dinv[v];
            float tot = bias[cc] + dv * (acc[idx] + bf2f(xws[vo]));
            float act = tot >= 0.f ? tot : NEG_SLOPE * tot;
            float xi  = XF32 ? xinf[vo] : bf2f(xinh[vo]);
            float xn  = act + xi;
            xout[vo] = f2bf(xn);
            rout[vo] = rin[vo] + xn * scale;
        }
    }
}

extern "C" void kernel_launch(void* const* d_in, const int* in_sizes, int n_in,
                              void* d_out, int out_size, void* d_ws, size_t ws_size,
                              hipStream_t stream) {
    const float* X   = (const float*)d_in[0];
    const int*   adj = (const int*)d_in[1];
    const float* W   = (const float*)d_in[2];
    const float* b   = (const float*)d_in[3];
    float* out = (float*)d_out;

    const int nd = in_sizes[0];          // N * 64
    const int n  = nd >> 6;              // N
    const int e  = in_sizes[1] / 2;      // E
    const int L  = in_sizes[3] / 64;     // layers (3)

    const int* src = adj;
    const int* dst = adj + e;

    const int nbk = (n + BSZ - 1) >> BSHIFT;             // ~391
    const int nch = (e + CHUNK - 1) / CHUNK;             // ~39
    const int M   = nbk * nch;                           // <= 16384

    // workspace layout (all 4B types; keep 16B alignment between arrays)
    unsigned* ebuf   = (unsigned*)d_ws;                  // e u32
    int*      m      = (int*)(ebuf + e);                 // 16384
    float*    dinv   = (float*)(m + 16384);              // n
    size_t    off    = ((size_t)(n + 3) & ~(size_t)3);   // pad to 16B
    ushort_t* Xcur   = (ushort_t*)(dinv + off);          // nd bf16
    ushort_t* xws    = Xcur + (size_t)nd + 64;           // nd + 64 bf16 (sentinel)

    // ---- preprocessing: bucket-grouped edge build (no CSR, no global atomics) ----
    hist_kernel<<<nch, 1024, 0, stream>>>(dst, m, xws, e, nbk, nch, n);
    scanm_kernel<<<1, 1024, 0, stream>>>(m, M);
    reorder_kernel<<<nch, 1024, 0, stream>>>(src, dst, m, ebuf, e, nbk, nch);
    bucket_deg_kernel<<<nbk, 1024, 0, stream>>>(ebuf, m, dinv, e, nbk, nch, n);

    // ---- layers ----
    int gemm_blocks = (n + 63) / 64;
    for (int i = 0; i < L; ++i) {
        const float* Wi = W + (size_t)i * 64 * 64;
        const float* bi = b + (size_t)i * 64;
        if (i == 0) {
            gemm_rl<1><<<gemm_blocks, 256, 0, stream>>>(X, nullptr, Wi, dinv, xws, n);
            agg_lds_kernel<1><<<nbk, 1024, 0, stream>>>(
                xws, ebuf, m, dinv, bi, X, nullptr, Xcur, X, out,
                1.0f / 2.0f, e, nbk, nch, n);
        } else {
            gemm_rl<0><<<gemm_blocks, 256, 0, stream>>>(nullptr, Xcur, Wi, dinv, xws, n);
            agg_lds_kernel<0><<<nbk, 1024, 0, stream>>>(
                xws, ebuf, m, dinv, bi, nullptr, Xcur, Xcur, out, out,
                1.0f / (float)(i + 2), e, nbk, nch, n);
        }
    }
}

// Round 9
// 351.140 us; speedup vs baseline: 5.2210x; 5.2210x over previous
//
#include <hip/hip_runtime.h>

#define NEG_SLOPE 0.01f
typedef unsigned short ushort_t;

#define CHUNK 16384       // edges per histogram/reorder block
#define BSHIFT 9          // 512 nodes per dst-bucket
#define BSZ 512
#define SRCMASK 0x7FFFFFu // low 23 bits = src, high 9 bits = dst-local

static __device__ __forceinline__ float bf2f(ushort_t u) {
    return __uint_as_float(((unsigned int)u) << 16);
}
static __device__ __forceinline__ ushort_t f2bf(float f) {
    unsigned int x = __float_as_uint(f);
    x += 0x7fffu + ((x >> 16) & 1u);   // round-to-nearest-even
    return (ushort_t)(x >> 16);
}
static __device__ __forceinline__ float bcastf(float v, int lane) {
    return __int_as_float(__builtin_amdgcn_readlane(__float_as_int(v), lane));
}

// ---------------------------------------------------------------------------
// phase A: per-chunk dst-bucket histogram (LDS only) + zero xws sentinel row
// ---------------------------------------------------------------------------
__global__ __launch_bounds__(1024) void hist_kernel(const int* __restrict__ dst,
                                                    int* __restrict__ m,
                                                    ushort_t* __restrict__ xws,
                                                    int e, int nbk, int nch, int n) {
    __shared__ int lcnt[256];
    int t = threadIdx.x;
    if (t < 256) lcnt[t] = 0;
    __syncthreads();
    int base = blockIdx.x * CHUNK;
    int lim  = e - base; if (lim > CHUNK) lim = CHUNK;
    for (int j = t; j < lim; j += 1024)
        atomicAdd(&lcnt[dst[base + j] >> BSHIFT], 1);
    __syncthreads();
    if (t < nbk) m[t * nch + blockIdx.x] = lcnt[t];   // bucket-major
    if (blockIdx.x == 0 && t < 64) xws[(size_t)n * 64 + t] = 0;  // sentinel row
}

// exclusive scan of m[0..M) in place (single block, 16/thread, M<=16384);
// also zeroes the global allocator
__global__ __launch_bounds__(1024) void scanm_kernel(int* __restrict__ m, int M,
                                                     int* __restrict__ galloc) {
    __shared__ int ts[1024];
    int t = threadIdx.x;
    int v[16], p[16];
    int s = 0;
    #pragma unroll
    for (int j = 0; j < 16; ++j) {
        int idx = t * 16 + j;
        v[j] = (idx < M) ? m[idx] : 0;
        s += v[j];
        p[j] = s;
    }
    ts[t] = s;
    __syncthreads();
    for (int st = 1; st < 1024; st <<= 1) {
        int x = (t >= st) ? ts[t - st] : 0;
        __syncthreads();
        ts[t] += x;
        __syncthreads();
    }
    int texcl = (t == 0) ? 0 : ts[t - 1];
    #pragma unroll
    for (int j = 0; j < 16; ++j) {
        int idx = t * 16 + j;
        if (idx < M) m[idx] = texcl + p[j] - v[j];
    }
    if (t == 0) *galloc = 0;
}

// phase B: reorder edges into bucket-grouped ebuf; packed u32 = src | dloc<<23
__global__ __launch_bounds__(1024) void reorder_kernel(const int* __restrict__ src,
                                                       const int* __restrict__ dst,
                                                       const int* __restrict__ m,
                                                       unsigned* __restrict__ ebuf,
                                                       int e, int nbk, int nch) {
    __shared__ int cur[256];
    int t = threadIdx.x;
    if (t < nbk) cur[t] = m[t * nch + blockIdx.x];
    __syncthreads();
    int base = blockIdx.x * CHUNK;
    int lim  = e - base; if (lim > CHUNK) lim = CHUNK;
    for (int j = t; j < lim; j += 1024) {
        int i = base + j;
        int d = dst[i];
        int pos = atomicAdd(&cur[d >> BSHIFT], 1);
        ebuf[pos] = (unsigned)src[i] | ((unsigned)(d & (BSZ - 1)) << 23);
    }
}

// ---------------------------------------------------------------------------
// phase C (merged): per-bucket degree count -> dinv + rowinfo(start,plen),
// CSR space via one global atomic per block, fill CSR with LDS cursors,
// pad with sentinel n. One block per bucket; all csr writes L2-local.
// ---------------------------------------------------------------------------
__global__ __launch_bounds__(1024) void fillmerge_kernel(const unsigned* __restrict__ ebuf,
                                                         const int* __restrict__ m,
                                                         int* __restrict__ galloc,
                                                         int2* __restrict__ rowinfo,
                                                         float* __restrict__ dinv,
                                                         int* __restrict__ csr,
                                                         int e, int nbk, int nch, int n) {
    __shared__ int lc[BSZ];
    __shared__ int pref[BSZ];
    __shared__ int cur[BSZ];
    __shared__ int basesh;
    int t = threadIdx.x;
    int b = blockIdx.x;
    if (t < BSZ) lc[t] = 0;
    __syncthreads();
    int bs = m[b * nch];
    int be = (b + 1 < nbk) ? m[(b + 1) * nch] : e;
    for (int i = bs + t; i < be; i += 1024)
        atomicAdd(&lc[ebuf[i] >> 23], 1);
    __syncthreads();
    int v = (b << BSHIFT) + t;
    int deg = 0, pd = 0;
    if (t < BSZ && v < n) {
        deg = lc[t];
        pd  = (deg + 7) & ~7;
    }
    if (t < BSZ) pref[t] = pd;
    __syncthreads();
    for (int s = 1; s < BSZ; s <<= 1) {
        int x = (t < BSZ && t >= s) ? pref[t - s] : 0;
        __syncthreads();
        if (t < BSZ) pref[t] += x;
        __syncthreads();
    }
    if (t == 0) basesh = atomicAdd(galloc, pref[BSZ - 1]);
    __syncthreads();
    int base = basesh;
    int start = 0;
    if (t < BSZ) {
        start  = base + pref[t] - pd;
        cur[t] = start;
        if (v < n) {
            rowinfo[v] = make_int2(start, pd);
            dinv[v]    = rsqrtf((float)deg + 1.0f);
        }
    }
    __syncthreads();
    for (int i = bs + t; i < be; i += 1024) {
        unsigned ev = ebuf[i];
        int slot = atomicAdd(&cur[ev >> 23], 1);
        csr[slot] = (int)(ev & SRCMASK);
    }
    __syncthreads();
    if (t < BSZ && v < n) {
        int endp = start + pd;
        for (int s2 = cur[t]; s2 < endp; ++s2) csr[s2] = n;   // pad sentinels
    }
}

// ---------------------------------------------------------------------------
// xws = (Xc @ W) * dinv[row]  (bf16 out). W column in lane VGPRs; X rows
// broadcast via readlane. XF32=1: f32 input (layer 0); else bf16.
// ---------------------------------------------------------------------------
template<int XF32>
__global__ __launch_bounds__(256) void gemm_rl(const float* __restrict__ Xf,
                                               const ushort_t* __restrict__ Xh,
                                               const float* __restrict__ W,
                                               const float* __restrict__ dinv,
                                               ushort_t* __restrict__ xws, int n) {
    int lane = threadIdx.x & 63;
    int wv   = threadIdx.x >> 6;

    float Wreg[64];
    #pragma unroll
    for (int k = 0; k < 64; ++k) Wreg[k] = W[k * 64 + lane];

    int row0 = blockIdx.x * 64 + wv * 16;
    int lr = lane >> 4;
    int lc = lane & 15;

    #pragma unroll 1
    for (int it = 0; it < 4; ++it) {
        int r = row0 + it * 4;
        float xr[4] = {0.f, 0.f, 0.f, 0.f};
        if (r + lr < n) {
            if (XF32) {
                float4 xv = *(const float4*)(Xf + (size_t)(r + lr) * 64 + lc * 4);
                xr[0] = xv.x; xr[1] = xv.y; xr[2] = xv.z; xr[3] = xv.w;
            } else {
                uint2 q = *(const uint2*)(Xh + (size_t)(r + lr) * 64 + lc * 4);
                xr[0] = bf2f((ushort_t)(q.x & 0xFFFF));
                xr[1] = bf2f((ushort_t)(q.x >> 16));
                xr[2] = bf2f((ushort_t)(q.y & 0xFFFF));
                xr[3] = bf2f((ushort_t)(q.y >> 16));
            }
        }
        float a0 = 0.f, a1 = 0.f, a2 = 0.f, a3 = 0.f;
        #pragma unroll
        for (int k = 0; k < 64; ++k) {
            float w = Wreg[k];
            a0 = fmaf(bcastf(xr[k & 3],      (k >> 2)), w, a0);
            a1 = fmaf(bcastf(xr[k & 3], 16 + (k >> 2)), w, a1);
            a2 = fmaf(bcastf(xr[k & 3], 32 + (k >> 2)), w, a2);
            a3 = fmaf(bcastf(xr[k & 3], 48 + (k >> 2)), w, a3);
        }
        if (r + 0 < n) xws[(size_t)(r + 0) * 64 + lane] = f2bf(a0 * dinv[r + 0]);
        if (r + 1 < n) xws[(size_t)(r + 1) * 64 + lane] = f2bf(a1 * dinv[r + 1]);
        if (r + 2 < n) xws[(size_t)(r + 2) * 64 + lane] = f2bf(a2 * dinv[r + 2]);
        if (r + 3 < n) xws[(size_t)(r + 3) * 64 + lane] = f2bf(a3 * dinv[r + 3]);
    }
}

// ---------------------------------------------------------------------------
// pull aggregation: TWO nodes per wave, interleaved 8+8 gather groups,
// register accumulation. leakyReLU + residual fused; xout bf16 only
// (running sum deferred to final_kernel). Segments padded to 8 w/ sentinels.
// ---------------------------------------------------------------------------
template<int XF32>
__global__ __launch_bounds__(256) void agg_kernel(
        const ushort_t* __restrict__ xws,
        const int2* __restrict__ rowinfo,
        const int* __restrict__ csr,
        const float* __restrict__ dinv,
        const float* __restrict__ bias,
        const float* __restrict__ xinf,    // f32 input (layer 0)
        const ushort_t* __restrict__ xinh, // bf16 input (layers >0)
        ushort_t* __restrict__ xout,
        int n) {
    int tid = threadIdx.x;
    int c   = tid & 63;
    int w   = blockIdx.x * 4 + (tid >> 6);
    int v0  = w * 2;
    if (v0 >= n) return;
    int  v1   = v0 + 1;
    bool has1 = (v1 < n);
    int  v1c  = has1 ? v1 : v0;

    int2 ri0 = rowinfo[v0];
    int2 ri1 = rowinfo[v1c];
    int b0 = ri0.x, len0 = ri0.y;
    int b1 = ri1.x, len1 = has1 ? ri1.y : 0;

    size_t vo0 = (size_t)v0  * 64 + c;
    size_t vo1 = (size_t)v1c * 64 + c;
    float acc0 = bf2f(xws[vo0]);     // self term (pre-scaled by dinv)
    float acc1 = bf2f(xws[vo1]);

    int mxlen = len0 > len1 ? len0 : len1;
    for (int off = 0; off < mxlen; off += 64) {
        int r0 = len0 - off;
        int r1 = len1 - off;
        int ce0 = (c < r0) ? csr[b0 + off + c] : n;
        int ce1 = (c < r1) ? csr[b1 + off + c] : n;
        int m0 = r0 < 64 ? r0 : 64;           // multiple of 8 (or <=0)
        int m1 = r1 < 64 ? r1 : 64;
        int mx = m0 > m1 ? m0 : m1;
        for (int j0 = 0; j0 < mx; j0 += 8) {
            float g0[8], g1[8];
            bool p0 = j0 < m0, p1 = j0 < m1;
            if (p0) {
                #pragma unroll
                for (int j = 0; j < 8; ++j) {
                    int s = __builtin_amdgcn_readlane(ce0, j0 + j);
                    g0[j] = bf2f(xws[(size_t)(unsigned)s * 64 + c]);
                }
            }
            if (p1) {
                #pragma unroll
                for (int j = 0; j < 8; ++j) {
                    int s = __builtin_amdgcn_readlane(ce1, j0 + j);
                    g1[j] = bf2f(xws[(size_t)(unsigned)s * 64 + c]);
                }
            }
            if (p0) {
                #pragma unroll
                for (int j = 0; j < 8; ++j) acc0 += g0[j];
            }
            if (p1) {
                #pragma unroll
                for (int j = 0; j < 8; ++j) acc1 += g1[j];
            }
        }
    }

    float dv0 = dinv[v0];
    float t0  = bias[c] + dv0 * acc0;
    float a0  = t0 >= 0.f ? t0 : NEG_SLOPE * t0;
    float xn0 = a0 + (XF32 ? xinf[vo0] : bf2f(xinh[vo0]));
    xout[vo0] = f2bf(xn0);
    if (has1) {
        float dv1 = dinv[v1];
        float t1  = bias[c] + dv1 * acc1;
        float a1  = t1 >= 0.f ? t1 : NEG_SLOPE * t1;
        float xn1 = a1 + (XF32 ? xinf[vo1] : bf2f(xinh[vo1]));
        xout[vo1] = f2bf(xn1);
    }
}

// ---------------------------------------------------------------------------
// final: out = X + x1/2 + x2/3 + x3/4   (4 elems per thread, vectorized)
// ---------------------------------------------------------------------------
__global__ __launch_bounds__(256) void final_kernel(const float* __restrict__ X,
                                                    const ushort_t* __restrict__ x1,
                                                    const ushort_t* __restrict__ x2,
                                                    const ushort_t* __restrict__ x3,
                                                    float* __restrict__ out, int nq) {
    int i = blockIdx.x * 256 + threadIdx.x;
    if (i >= nq) return;
    float4 xv = ((const float4*)X)[i];
    uint2 a = ((const uint2*)x1)[i];
    uint2 b = ((const uint2*)x2)[i];
    uint2 d = ((const uint2*)x3)[i];
    float4 o;
    o.x = xv.x + 0.5f * bf2f((ushort_t)(a.x & 0xFFFF)) + (1.f/3.f) * bf2f((ushort_t)(b.x & 0xFFFF)) + 0.25f * bf2f((ushort_t)(d.x & 0xFFFF));
    o.y = xv.y + 0.5f * bf2f((ushort_t)(a.x >> 16))    + (1.f/3.f) * bf2f((ushort_t)(b.x >> 16))    + 0.25f * bf2f((ushort_t)(d.x >> 16));
    o.z = xv.z + 0.5f * bf2f((ushort_t)(a.y & 0xFFFF)) + (1.f/3.f) * bf2f((ushort_t)(b.y & 0xFFFF)) + 0.25f * bf2f((ushort_t)(d.y & 0xFFFF));
    o.w = xv.w + 0.5f * bf2f((ushort_t)(a.y >> 16))    + (1.f/3.f) * bf2f((ushort_t)(b.y >> 16))    + 0.25f * bf2f((ushort_t)(d.y >> 16));
    ((float4*)out)[i] = o;
}

extern "C" void kernel_launch(void* const* d_in, const int* in_sizes, int n_in,
                              void* d_out, int out_size, void* d_ws, size_t ws_size,
                              hipStream_t stream) {
    const float* X   = (const float*)d_in[0];
    const int*   adj = (const int*)d_in[1];
    const float* W   = (const float*)d_in[2];
    const float* b   = (const float*)d_in[3];
    float* out = (float*)d_out;

    const int nd = in_sizes[0];          // N * 64
    const int n  = nd >> 6;              // N
    const int e  = in_sizes[1] / 2;      // E

    const int* src = adj;
    const int* dst = adj + e;

    const int nbk = (n + BSZ - 1) >> BSHIFT;             // ~196
    const int nch = (e + CHUNK - 1) / CHUNK;             // ~77
    const int M   = nbk * nch;                           // <= 16384
    const int csr_len = e + 8 * n + 64;

    // workspace layout
    unsigned* ebuf   = (unsigned*)d_ws;                  // e u32
    int*      csr    = (int*)(ebuf + e);                 // csr_len
    int*      m      = csr + csr_len;                    // 16384
    int*      galloc = m + 16384;                        // 4 (16B pad)
    int2*     rowinfo= (int2*)(galloc + 4);              // n int2
    float*    dinv   = (float*)(rowinfo + n);            // n
    size_t    off    = ((size_t)(n + 3) & ~(size_t)3);
    ushort_t* xws    = (ushort_t*)(dinv + off);          // nd + 64
    ushort_t* x1     = xws + (size_t)nd + 64;            // nd
    ushort_t* x2     = x1  + (size_t)nd;                 // nd
    ushort_t* x3     = x2  + (size_t)nd;                 // nd

    // ---- preprocessing ----
    hist_kernel<<<nch, 1024, 0, stream>>>(dst, m, xws, e, nbk, nch, n);
    scanm_kernel<<<1, 1024, 0, stream>>>(m, M, galloc);
    reorder_kernel<<<nch, 1024, 0, stream>>>(src, dst, m, ebuf, e, nbk, nch);
    fillmerge_kernel<<<nbk, 1024, 0, stream>>>(ebuf, m, galloc, rowinfo, dinv,
                                               csr, e, nbk, nch, n);

    // ---- layers ----
    int gemm_blocks = (n + 63) / 64;
    int agg_blocks  = (n + 7) / 8;       // 2 nodes/wave, 4 waves/block
    // layer 0 (f32 X in, bf16 x1 out)
    gemm_rl<1><<<gemm_blocks, 256, 0, stream>>>(X, nullptr, W, dinv, xws, n);
    agg_kernel<1><<<agg_blocks, 256, 0, stream>>>(xws, rowinfo, csr, dinv, b,
                                                  X, nullptr, x1, n);
    // layer 1
    gemm_rl<0><<<gemm_blocks, 256, 0, stream>>>(nullptr, x1, W + 4096, dinv, xws, n);
    agg_kernel<0><<<agg_blocks, 256, 0, stream>>>(xws, rowinfo, csr, dinv, b + 64,
                                                  nullptr, x1, x2, n);
    // layer 2
    gemm_rl<0><<<gemm_blocks, 256, 0, stream>>>(nullptr, x2, W + 8192, dinv, xws, n);
    agg_kernel<0><<<agg_blocks, 256, 0, stream>>>(xws, rowinfo, csr, dinv, b + 128,
                                                  nullptr, x2, x3, n);
    // combine
    int nq = nd >> 2;
    final_kernel<<<(nq + 255) / 256, 256, 0, stream>>>(X, x1, x2, x3, out, nq);
}

// Round 10
// 237.352 us; speedup vs baseline: 7.7240x; 1.4794x over previous
//
#include <hip/hip_runtime.h>

#define NEG_SLOPE 0.01f
typedef unsigned short ushort_t;

#define CHUNK 16384       // edges per histogram/reorder block
#define BSHIFT 9          // 512 nodes per dst-bucket
#define BSZ 512
#define SRCMASK 0x7FFFFFu // low 23 bits = src, high 9 bits = dst-local

typedef __attribute__((ext_vector_type(8))) short short8;
typedef __attribute__((ext_vector_type(4))) float f32x4;

static __device__ __forceinline__ float bf2f(ushort_t u) {
    return __uint_as_float(((unsigned int)u) << 16);
}
static __device__ __forceinline__ ushort_t f2bf(float f) {
    unsigned int x = __float_as_uint(f);
    x += 0x7fffu + ((x >> 16) & 1u);   // round-to-nearest-even
    return (ushort_t)(x >> 16);
}

// ---------------------------------------------------------------------------
// phase A: per-chunk dst-bucket histogram (LDS only) + zero xws sentinel row
// ---------------------------------------------------------------------------
__global__ __launch_bounds__(1024) void hist_kernel(const int* __restrict__ dst,
                                                    int* __restrict__ m,
                                                    ushort_t* __restrict__ xws,
                                                    int e, int nbk, int nch, int n) {
    __shared__ int lcnt[256];
    int t = threadIdx.x;
    if (t < 256) lcnt[t] = 0;
    __syncthreads();
    int base = blockIdx.x * CHUNK;
    int lim  = e - base; if (lim > CHUNK) lim = CHUNK;
    for (int j = t; j < lim; j += 1024)
        atomicAdd(&lcnt[dst[base + j] >> BSHIFT], 1);
    __syncthreads();
    if (t < nbk) m[t * nch + blockIdx.x] = lcnt[t];   // bucket-major
    if (blockIdx.x == 0 && t < 64) xws[(size_t)n * 64 + t] = 0;  // sentinel row
}

// exclusive scan of m[0..M) in place (single block, 16/thread, M<=16384);
// also zeroes the global allocator
__global__ __launch_bounds__(1024) void scanm_kernel(int* __restrict__ m, int M,
                                                     int* __restrict__ galloc) {
    __shared__ int ts[1024];
    int t = threadIdx.x;
    int v[16], p[16];
    int s = 0;
    #pragma unroll
    for (int j = 0; j < 16; ++j) {
        int idx = t * 16 + j;
        v[j] = (idx < M) ? m[idx] : 0;
        s += v[j];
        p[j] = s;
    }
    ts[t] = s;
    __syncthreads();
    for (int st = 1; st < 1024; st <<= 1) {
        int x = (t >= st) ? ts[t - st] : 0;
        __syncthreads();
        ts[t] += x;
        __syncthreads();
    }
    int texcl = (t == 0) ? 0 : ts[t - 1];
    #pragma unroll
    for (int j = 0; j < 16; ++j) {
        int idx = t * 16 + j;
        if (idx < M) m[idx] = texcl + p[j] - v[j];
    }
    if (t == 0) *galloc = 0;
}

// phase B: reorder edges into bucket-grouped ebuf; packed u32 = src | dloc<<23
__global__ __launch_bounds__(1024) void reorder_kernel(const int* __restrict__ src,
                                                       const int* __restrict__ dst,
                                                       const int* __restrict__ m,
                                                       unsigned* __restrict__ ebuf,
                                                       int e, int nbk, int nch) {
    __shared__ int cur[256];
    int t = threadIdx.x;
    if (t < nbk) cur[t] = m[t * nch + blockIdx.x];
    __syncthreads();
    int base = blockIdx.x * CHUNK;
    int lim  = e - base; if (lim > CHUNK) lim = CHUNK;
    for (int j = t; j < lim; j += 1024) {
        int i = base + j;
        int d = dst[i];
        int pos = atomicAdd(&cur[d >> BSHIFT], 1);
        ebuf[pos] = (unsigned)src[i] | ((unsigned)(d & (BSZ - 1)) << 23);
    }
}

// ---------------------------------------------------------------------------
// phase C (merged): per-bucket degree count -> dinv + rowinfo(start,plen),
// CSR space via one global atomic per block, fill CSR with LDS cursors,
// pad with sentinel n. One block per bucket; all csr writes L2-local.
// ---------------------------------------------------------------------------
__global__ __launch_bounds__(1024) void fillmerge_kernel(const unsigned* __restrict__ ebuf,
                                                         const int* __restrict__ m,
                                                         int* __restrict__ galloc,
                                                         int2* __restrict__ rowinfo,
                                                         float* __restrict__ dinv,
                                                         int* __restrict__ csr,
                                                         int e, int nbk, int nch, int n) {
    __shared__ int lc[BSZ];
    __shared__ int pref[BSZ];
    __shared__ int cur[BSZ];
    __shared__ int basesh;
    int t = threadIdx.x;
    int b = blockIdx.x;
    if (t < BSZ) lc[t] = 0;
    __syncthreads();
    int bs = m[b * nch];
    int be = (b + 1 < nbk) ? m[(b + 1) * nch] : e;
    for (int i = bs + t; i < be; i += 1024)
        atomicAdd(&lc[ebuf[i] >> 23], 1);
    __syncthreads();
    int v = (b << BSHIFT) + t;
    int deg = 0, pd = 0;
    if (t < BSZ && v < n) {
        deg = lc[t];
        pd  = (deg + 7) & ~7;
    }
    if (t < BSZ) pref[t] = pd;
    __syncthreads();
    for (int s = 1; s < BSZ; s <<= 1) {
        int x = (t < BSZ && t >= s) ? pref[t - s] : 0;
        __syncthreads();
        if (t < BSZ) pref[t] += x;
        __syncthreads();
    }
    if (t == 0) basesh = atomicAdd(galloc, pref[BSZ - 1]);
    __syncthreads();
    int base = basesh;
    int start = 0;
    if (t < BSZ) {
        start  = base + pref[t] - pd;
        cur[t] = start;
        if (v < n) {
            rowinfo[v] = make_int2(start, pd);
            dinv[v]    = rsqrtf((float)deg + 1.0f);
        }
    }
    __syncthreads();
    for (int i = bs + t; i < be; i += 1024) {
        unsigned ev = ebuf[i];
        int slot = atomicAdd(&cur[ev >> 23], 1);
        csr[slot] = (int)(ev & SRCMASK);
    }
    __syncthreads();
    if (t < BSZ && v < n) {
        int endp = start + pd;
        for (int s2 = cur[t]; s2 < endp; ++s2) csr[s2] = n;   // pad sentinels
    }
}

// ---------------------------------------------------------------------------
// pack W[layer] (64x64 f32) into MFMA B-fragment layout, bf16:
// wfrag[layer][f8][lane][e] = bf16(W[lg*8+e+32*f][cg*16+(lane&15)])
// where f8 = cg*2+f, lg = lane>>4. One block per layer.
// ---------------------------------------------------------------------------
__global__ __launch_bounds__(256) void packw_kernel(const float* __restrict__ W,
                                                    ushort_t* __restrict__ wfrag) {
    int t    = threadIdx.x;
    int lane = t & 63;
    int lg   = lane >> 4;
    int li   = lane & 15;
    const float* Wl = W + (size_t)blockIdx.x * 4096;
    ushort_t* outp  = wfrag + (size_t)blockIdx.x * 4096;
    #pragma unroll
    for (int ff = 0; ff < 2; ++ff) {
        int f8 = (t >> 6) * 2 + ff;
        int cg = f8 >> 1, f = f8 & 1;
        #pragma unroll
        for (int e = 0; e < 8; ++e) {
            int k   = lg * 8 + e + 32 * f;
            int col = cg * 16 + li;
            outp[(f8 * 64 + lane) * 8 + e] = f2bf(Wl[k * 64 + col]);
        }
    }
}

// ---------------------------------------------------------------------------
// MFMA gemm: xws = (Xin @ W) * dinv[row], bf16 out.
// Per wave: 64 rows (4 slabs of 16), 8 B-frags held in VGPRs, 8 MFMA/slab.
// A/B packed with the same k-bijection (lg*8+e+32f) -> sum over k is exact.
// C/D layout (verified m89): col = lane&15, row = (lane>>4)*4 + reg.
// ---------------------------------------------------------------------------
template<int XF32>
__global__ __launch_bounds__(256) void gemm_mfma(const float* __restrict__ Xf,
                                                 const ushort_t* __restrict__ Xh,
                                                 const ushort_t* __restrict__ wfrag,
                                                 const float* __restrict__ dinv,
                                                 ushort_t* __restrict__ xws, int n) {
    int lane = threadIdx.x & 63;
    int wv   = threadIdx.x >> 6;
    int lg   = lane >> 4;
    int li   = lane & 15;

    short8 bfr[8];
    const short8* wp = (const short8*)wfrag;
    #pragma unroll
    for (int f8 = 0; f8 < 8; ++f8) bfr[f8] = wp[f8 * 64 + lane];

    int row0 = (blockIdx.x * 4 + wv) * 64;

    #pragma unroll 1
    for (int it = 0; it < 4; ++it) {
        int rbase = row0 + it * 16;
        if (rbase >= n) break;          // n % 16 == 0 assumed; rows rbase..+15 valid
        int r = rbase + li;             // A row = lane&15

        short8 afr[2];
        if (XF32) {
            #pragma unroll
            for (int f = 0; f < 2; ++f) {
                const float* p = Xf + (size_t)r * 64 + lg * 8 + 32 * f;
                float4 c0 = *(const float4*)(p);
                float4 c1 = *(const float4*)(p + 4);
                short8 a;
                a[0] = (short)f2bf(c0.x); a[1] = (short)f2bf(c0.y);
                a[2] = (short)f2bf(c0.z); a[3] = (short)f2bf(c0.w);
                a[4] = (short)f2bf(c1.x); a[5] = (short)f2bf(c1.y);
                a[6] = (short)f2bf(c1.z); a[7] = (short)f2bf(c1.w);
                afr[f] = a;
            }
        } else {
            const ushort_t* p = Xh + (size_t)r * 64 + lg * 8;
            afr[0] = *(const short8*)(p);
            afr[1] = *(const short8*)(p + 32);
        }

        float dv[4];
        #pragma unroll
        for (int reg = 0; reg < 4; ++reg) dv[reg] = dinv[rbase + lg * 4 + reg];

        #pragma unroll
        for (int cg = 0; cg < 4; ++cg) {
            f32x4 acc = {0.f, 0.f, 0.f, 0.f};
            acc = __builtin_amdgcn_mfma_f32_16x16x32_bf16(afr[0], bfr[cg * 2 + 0], acc, 0, 0, 0);
            acc = __builtin_amdgcn_mfma_f32_16x16x32_bf16(afr[1], bfr[cg * 2 + 1], acc, 0, 0, 0);
            #pragma unroll
            for (int reg = 0; reg < 4; ++reg) {
                int rr = rbase + lg * 4 + reg;
                xws[(size_t)rr * 64 + cg * 16 + li] = f2bf(acc[reg] * dv[reg]);
            }
        }
    }
}

// ---------------------------------------------------------------------------
// pull aggregation: TWO nodes per wave, interleaved 8+8 gather groups,
// register accumulation. leakyReLU + residual fused; xout bf16 only.
// ---------------------------------------------------------------------------
template<int XF32>
__global__ __launch_bounds__(256) void agg_kernel(
        const ushort_t* __restrict__ xws,
        const int2* __restrict__ rowinfo,
        const int* __restrict__ csr,
        const float* __restrict__ dinv,
        const float* __restrict__ bias,
        const float* __restrict__ xinf,    // f32 input (layer 0)
        const ushort_t* __restrict__ xinh, // bf16 input (layers >0)
        ushort_t* __restrict__ xout,
        int n) {
    int tid = threadIdx.x;
    int c   = tid & 63;
    int w   = blockIdx.x * 4 + (tid >> 6);
    int v0  = w * 2;
    if (v0 >= n) return;
    int  v1   = v0 + 1;
    bool has1 = (v1 < n);
    int  v1c  = has1 ? v1 : v0;

    int2 ri0 = rowinfo[v0];
    int2 ri1 = rowinfo[v1c];
    int b0 = ri0.x, len0 = ri0.y;
    int b1 = ri1.x, len1 = has1 ? ri1.y : 0;

    size_t vo0 = (size_t)v0  * 64 + c;
    size_t vo1 = (size_t)v1c * 64 + c;
    float acc0 = bf2f(xws[vo0]);     // self term (pre-scaled by dinv)
    float acc1 = bf2f(xws[vo1]);

    int mxlen = len0 > len1 ? len0 : len1;
    for (int off = 0; off < mxlen; off += 64) {
        int r0 = len0 - off;
        int r1 = len1 - off;
        int ce0 = (c < r0) ? csr[b0 + off + c] : n;
        int ce1 = (c < r1) ? csr[b1 + off + c] : n;
        int m0 = r0 < 64 ? r0 : 64;           // multiple of 8 (or <=0)
        int m1 = r1 < 64 ? r1 : 64;
        int mx = m0 > m1 ? m0 : m1;
        for (int j0 = 0; j0 < mx; j0 += 8) {
            float g0[8], g1[8];
            bool p0 = j0 < m0, p1 = j0 < m1;
            if (p0) {
                #pragma unroll
                for (int j = 0; j < 8; ++j) {
                    int s = __builtin_amdgcn_readlane(ce0, j0 + j);
                    g0[j] = bf2f(xws[(size_t)(unsigned)s * 64 + c]);
                }
            }
            if (p1) {
                #pragma unroll
                for (int j = 0; j < 8; ++j) {
                    int s = __builtin_amdgcn_readlane(ce1, j0 + j);
                    g1[j] = bf2f(xws[(size_t)(unsigned)s * 64 + c]);
                }
            }
            if (p0) {
                #pragma unroll
                for (int j = 0; j < 8; ++j) acc0 += g0[j];
            }
            if (p1) {
                #pragma unroll
                for (int j = 0; j < 8; ++j) acc1 += g1[j];
            }
        }
    }

    float dv0 = dinv[v0];
    float t0  = bias[c] + dv0 * acc0;
    float a0  = t0 >= 0.f ? t0 : NEG_SLOPE * t0;
    float xn0 = a0 + (XF32 ? xinf[vo0] : bf2f(xinh[vo0]));
    xout[vo0] = f2bf(xn0);
    if (has1) {
        float dv1 = dinv[v1];
        float t1  = bias[c] + dv1 * acc1;
        float a1  = t1 >= 0.f ? t1 : NEG_SLOPE * t1;
        float xn1 = a1 + (XF32 ? xinf[vo1] : bf2f(xinh[vo1]));
        xout[vo1] = f2bf(xn1);
    }
}

// ---------------------------------------------------------------------------
// final: out = X + x1/2 + x2/3 + x3/4   (4 elems per thread, vectorized)
// ---------------------------------------------------------------------------
__global__ __launch_bounds__(256) void final_kernel(const float* __restrict__ X,
                                                    const ushort_t* __restrict__ x1,
                                                    const ushort_t* __restrict__ x2,
                                                    const ushort_t* __restrict__ x3,
                                                    float* __restrict__ out, int nq) {
    int i = blockIdx.x * 256 + threadIdx.x;
    if (i >= nq) return;
    float4 xv = ((const float4*)X)[i];
    uint2 a = ((const uint2*)x1)[i];
    uint2 b = ((const uint2*)x2)[i];
    uint2 d = ((const uint2*)x3)[i];
    float4 o;
    o.x = xv.x + 0.5f * bf2f((ushort_t)(a.x & 0xFFFF)) + (1.f/3.f) * bf2f((ushort_t)(b.x & 0xFFFF)) + 0.25f * bf2f((ushort_t)(d.x & 0xFFFF));
    o.y = xv.y + 0.5f * bf2f((ushort_t)(a.x >> 16))    + (1.f/3.f) * bf2f((ushort_t)(b.x >> 16))    + 0.25f * bf2f((ushort_t)(d.x >> 16));
    o.z = xv.z + 0.5f * bf2f((ushort_t)(a.y & 0xFFFF)) + (1.f/3.f) * bf2f((ushort_t)(b.y & 0xFFFF)) + 0.25f * bf2f((ushort_t)(d.y & 0xFFFF));
    o.w = xv.w + 0.5f * bf2f((ushort_t)(a.y >> 16))    + (1.f/3.f) * bf2f((ushort_t)(b.y >> 16))    + 0.25f * bf2f((ushort_t)(d.y >> 16));
    ((float4*)out)[i] = o;
}

extern "C" void kernel_launch(void* const* d_in, const int* in_sizes, int n_in,
                              void* d_out, int out_size, void* d_ws, size_t ws_size,
                              hipStream_t stream) {
    const float* X   = (const float*)d_in[0];
    const int*   adj = (const int*)d_in[1];
    const float* W   = (const float*)d_in[2];
    const float* b   = (const float*)d_in[3];
    float* out = (float*)d_out;

    const int nd = in_sizes[0];          // N * 64
    const int n  = nd >> 6;              // N
    const int e  = in_sizes[1] / 2;      // E
    const int L  = in_sizes[3] / 64;     // layers (3)

    const int* src = adj;
    const int* dst = adj + e;

    const int nbk = (n + BSZ - 1) >> BSHIFT;             // ~196
    const int nch = (e + CHUNK - 1) / CHUNK;             // ~77
    const int M   = nbk * nch;                           // <= 16384
    const int csr_len = e + 8 * n + 64;

    // workspace layout
    unsigned* ebuf   = (unsigned*)d_ws;                  // e u32
    int*      csr    = (int*)(ebuf + e);                 // csr_len
    int*      m      = csr + csr_len;                    // 16384
    int*      galloc = m + 16384;                        // 4 (16B pad)
    ushort_t* wfrag  = (ushort_t*)(galloc + 4);          // 3 * 4096 bf16 (24KB)
    int2*     rowinfo= (int2*)(wfrag + 3 * 4096);        // n int2
    float*    dinv   = (float*)(rowinfo + n);            // n
    size_t    off    = ((size_t)(n + 3) & ~(size_t)3);
    ushort_t* xws    = (ushort_t*)(dinv + off);          // nd + 64
    ushort_t* x1     = xws + (size_t)nd + 64;            // nd
    ushort_t* x2     = x1  + (size_t)nd;                 // nd
    ushort_t* x3     = x2  + (size_t)nd;                 // nd

    // ---- preprocessing ----
    hist_kernel<<<nch, 1024, 0, stream>>>(dst, m, xws, e, nbk, nch, n);
    scanm_kernel<<<1, 1024, 0, stream>>>(m, M, galloc);
    reorder_kernel<<<nch, 1024, 0, stream>>>(src, dst, m, ebuf, e, nbk, nch);
    fillmerge_kernel<<<nbk, 1024, 0, stream>>>(ebuf, m, galloc, rowinfo, dinv,
                                               csr, e, nbk, nch, n);
    packw_kernel<<<L, 256, 0, stream>>>(W, wfrag);

    // ---- layers ----
    int gemm_blocks = (n + 255) / 256;   // 4 waves x 64 rows per block
    int agg_blocks  = (n + 7) / 8;       // 2 nodes/wave, 4 waves/block
    // layer 0 (f32 X in, bf16 x1 out)
    gemm_mfma<1><<<gemm_blocks, 256, 0, stream>>>(X, nullptr, wfrag, dinv, xws, n);
    agg_kernel<1><<<agg_blocks, 256, 0, stream>>>(xws, rowinfo, csr, dinv, b,
                                                  X, nullptr, x1, n);
    // layer 1
    gemm_mfma<0><<<gemm_blocks, 256, 0, stream>>>(nullptr, x1, wfrag + 4096, dinv, xws, n);
    agg_kernel<0><<<agg_blocks, 256, 0, stream>>>(xws, rowinfo, csr, dinv, b + 64,
                                                  nullptr, x1, x2, n);
    // layer 2
    gemm_mfma<0><<<gemm_blocks, 256, 0, stream>>>(nullptr, x2, wfrag + 8192, dinv, xws, n);
    agg_kernel<0><<<agg_blocks, 256, 0, stream>>>(xws, rowinfo, csr, dinv, b + 128,
                                                  nullptr, x2, x3, n);
    // combine
    int nq = nd >> 2;
    final_kernel<<<(nq + 255) / 256, 256, 0, stream>>>(X, x1, x2, x3, out, nq);
}

// Round 11
// 227.877 us; speedup vs baseline: 8.0452x; 1.0416x over previous
//
#include <hip/hip_runtime.h>

#define NEG_SLOPE 0.01f
typedef unsigned short ushort_t;

#define CHUNK 16384       // edges per histogram/reorder block
#define BSHIFT 9          // 512 nodes per dst-bucket
#define BSZ 512
#define SRCMASK 0x7FFFFFu // low 23 bits = src, high 9 bits = dst-local

typedef __attribute__((ext_vector_type(8))) short short8;
typedef __attribute__((ext_vector_type(4))) float f32x4;

static __device__ __forceinline__ float bf2f(ushort_t u) {
    return __uint_as_float(((unsigned int)u) << 16);
}
static __device__ __forceinline__ ushort_t f2bf(float f) {
    unsigned int x = __float_as_uint(f);
    x += 0x7fffu + ((x >> 16) & 1u);   // round-to-nearest-even
    return (ushort_t)(x >> 16);
}

// ---------------------------------------------------------------------------
// phase A: per-chunk dst-bucket histogram (LDS only) + zero xws sentinel row.
// Blocks >= nch instead pack W[layer] into MFMA B-fragment layout (bf16):
// wfrag[layer][f8][lane][e] = bf16(W[lg*8+e+32*f][cg*16+(lane&15)]),
// f8 = cg*2+f, lg = lane>>4.
// ---------------------------------------------------------------------------
__global__ __launch_bounds__(1024) void hist_kernel(const int* __restrict__ dst,
                                                    int* __restrict__ m,
                                                    ushort_t* __restrict__ xws,
                                                    const float* __restrict__ W,
                                                    ushort_t* __restrict__ wfrag,
                                                    int e, int nbk, int nch, int n) {
    int t = threadIdx.x;
    if (blockIdx.x >= nch) {               // W-pack blocks (one per layer)
        int layer = blockIdx.x - nch;
        if (t < 256) {
            int lane = t & 63;
            int lg   = lane >> 4;
            int li   = lane & 15;
            const float* Wl = W + (size_t)layer * 4096;
            ushort_t* outp  = wfrag + (size_t)layer * 4096;
            #pragma unroll
            for (int ff = 0; ff < 2; ++ff) {
                int f8 = (t >> 6) * 2 + ff;
                int cg = f8 >> 1, f = f8 & 1;
                #pragma unroll
                for (int ee = 0; ee < 8; ++ee) {
                    int k   = lg * 8 + ee + 32 * f;
                    int col = cg * 16 + li;
                    outp[(f8 * 64 + lane) * 8 + ee] = f2bf(Wl[k * 64 + col]);
                }
            }
        }
        return;
    }
    __shared__ int lcnt[256];
    if (t < 256) lcnt[t] = 0;
    __syncthreads();
    int base = blockIdx.x * CHUNK;
    int lim  = e - base; if (lim > CHUNK) lim = CHUNK;
    for (int j = t; j < lim; j += 1024)
        atomicAdd(&lcnt[dst[base + j] >> BSHIFT], 1);
    __syncthreads();
    if (t < nbk) m[t * nch + blockIdx.x] = lcnt[t];   // bucket-major
    if (blockIdx.x == 0 && t < 64) xws[(size_t)n * 64 + t] = 0;  // sentinel row
}

// exclusive scan of m[0..M) in place (single block, 16/thread, M<=16384);
// also zeroes the global allocator
__global__ __launch_bounds__(1024) void scanm_kernel(int* __restrict__ m, int M,
                                                     int* __restrict__ galloc) {
    __shared__ int ts[1024];
    int t = threadIdx.x;
    int v[16], p[16];
    int s = 0;
    #pragma unroll
    for (int j = 0; j < 16; ++j) {
        int idx = t * 16 + j;
        v[j] = (idx < M) ? m[idx] : 0;
        s += v[j];
        p[j] = s;
    }
    ts[t] = s;
    __syncthreads();
    for (int st = 1; st < 1024; st <<= 1) {
        int x = (t >= st) ? ts[t - st] : 0;
        __syncthreads();
        ts[t] += x;
        __syncthreads();
    }
    int texcl = (t == 0) ? 0 : ts[t - 1];
    #pragma unroll
    for (int j = 0; j < 16; ++j) {
        int idx = t * 16 + j;
        if (idx < M) m[idx] = texcl + p[j] - v[j];
    }
    if (t == 0) *galloc = 0;
}

// phase B: reorder edges into bucket-grouped ebuf; packed u32 = src | dloc<<23
__global__ __launch_bounds__(1024) void reorder_kernel(const int* __restrict__ src,
                                                       const int* __restrict__ dst,
                                                       const int* __restrict__ m,
                                                       unsigned* __restrict__ ebuf,
                                                       int e, int nbk, int nch) {
    __shared__ int cur[256];
    int t = threadIdx.x;
    if (t < nbk) cur[t] = m[t * nch + blockIdx.x];
    __syncthreads();
    int base = blockIdx.x * CHUNK;
    int lim  = e - base; if (lim > CHUNK) lim = CHUNK;
    for (int j = t; j < lim; j += 1024) {
        int i = base + j;
        int d = dst[i];
        int pos = atomicAdd(&cur[d >> BSHIFT], 1);
        ebuf[pos] = (unsigned)src[i] | ((unsigned)(d & (BSZ - 1)) << 23);
    }
}

// ---------------------------------------------------------------------------
// phase C (merged): per-bucket degree count -> dinv + rowinfo(start,plen),
// CSR space via one global atomic per block, fill CSR with LDS cursors,
// pad with sentinel n. One block per bucket; all csr writes L2-local.
// ---------------------------------------------------------------------------
__global__ __launch_bounds__(1024) void fillmerge_kernel(const unsigned* __restrict__ ebuf,
                                                         const int* __restrict__ m,
                                                         int* __restrict__ galloc,
                                                         int2* __restrict__ rowinfo,
                                                         float* __restrict__ dinv,
                                                         int* __restrict__ csr,
                                                         int e, int nbk, int nch, int n) {
    __shared__ int lc[BSZ];
    __shared__ int pref[BSZ];
    __shared__ int cur[BSZ];
    __shared__ int basesh;
    int t = threadIdx.x;
    int b = blockIdx.x;
    if (t < BSZ) lc[t] = 0;
    __syncthreads();
    int bs = m[b * nch];
    int be = (b + 1 < nbk) ? m[(b + 1) * nch] : e;
    for (int i = bs + t; i < be; i += 1024)
        atomicAdd(&lc[ebuf[i] >> 23], 1);
    __syncthreads();
    int v = (b << BSHIFT) + t;
    int deg = 0, pd = 0;
    if (t < BSZ && v < n) {
        deg = lc[t];
        pd  = (deg + 7) & ~7;
    }
    if (t < BSZ) pref[t] = pd;
    __syncthreads();
    for (int s = 1; s < BSZ; s <<= 1) {
        int x = (t < BSZ && t >= s) ? pref[t - s] : 0;
        __syncthreads();
        if (t < BSZ) pref[t] += x;
        __syncthreads();
    }
    if (t == 0) basesh = atomicAdd(galloc, pref[BSZ - 1]);
    __syncthreads();
    int base = basesh;
    int start = 0;
    if (t < BSZ) {
        start  = base + pref[t] - pd;
        cur[t] = start;
        if (v < n) {
            rowinfo[v] = make_int2(start, pd);
            dinv[v]    = rsqrtf((float)deg + 1.0f);
        }
    }
    __syncthreads();
    for (int i = bs + t; i < be; i += 1024) {
        unsigned ev = ebuf[i];
        int slot = atomicAdd(&cur[ev >> 23], 1);
        csr[slot] = (int)(ev & SRCMASK);
    }
    __syncthreads();
    if (t < BSZ && v < n) {
        int endp = start + pd;
        for (int s2 = cur[t]; s2 < endp; ++s2) csr[s2] = n;   // pad sentinels
    }
}

// ---------------------------------------------------------------------------
// MFMA gemm: xws = (Xin @ W) * dinv[row], bf16 out.
// Per wave: 64 rows (4 slabs of 16), 8 B-frags held in VGPRs, 8 MFMA/slab.
// A/B packed with the same k-bijection (lg*8+e+32f) -> sum over k is exact.
// C/D layout (verified m89): col = lane&15, row = (lane>>4)*4 + reg.
// ---------------------------------------------------------------------------
template<int XF32>
__global__ __launch_bounds__(256) void gemm_mfma(const float* __restrict__ Xf,
                                                 const ushort_t* __restrict__ Xh,
                                                 const ushort_t* __restrict__ wfrag,
                                                 const float* __restrict__ dinv,
                                                 ushort_t* __restrict__ xws, int n) {
    int lane = threadIdx.x & 63;
    int wv   = threadIdx.x >> 6;
    int lg   = lane >> 4;
    int li   = lane & 15;

    short8 bfr[8];
    const short8* wp = (const short8*)wfrag;
    #pragma unroll
    for (int f8 = 0; f8 < 8; ++f8) bfr[f8] = wp[f8 * 64 + lane];

    int row0 = (blockIdx.x * 4 + wv) * 64;

    #pragma unroll 1
    for (int it = 0; it < 4; ++it) {
        int rbase = row0 + it * 16;
        if (rbase >= n) break;          // rows rbase..+15 valid when rbase < n
        int r = rbase + li;             // A row = lane&15

        short8 afr[2];
        if (XF32) {
            #pragma unroll
            for (int f = 0; f < 2; ++f) {
                const float* p = Xf + (size_t)r * 64 + lg * 8 + 32 * f;
                float4 c0 = *(const float4*)(p);
                float4 c1 = *(const float4*)(p + 4);
                short8 a;
                a[0] = (short)f2bf(c0.x); a[1] = (short)f2bf(c0.y);
                a[2] = (short)f2bf(c0.z); a[3] = (short)f2bf(c0.w);
                a[4] = (short)f2bf(c1.x); a[5] = (short)f2bf(c1.y);
                a[6] = (short)f2bf(c1.z); a[7] = (short)f2bf(c1.w);
                afr[f] = a;
            }
        } else {
            const ushort_t* p = Xh + (size_t)r * 64 + lg * 8;
            afr[0] = *(const short8*)(p);
            afr[1] = *(const short8*)(p + 32);
        }

        float dv[4];
        #pragma unroll
        for (int reg = 0; reg < 4; ++reg) dv[reg] = dinv[rbase + lg * 4 + reg];

        #pragma unroll
        for (int cg = 0; cg < 4; ++cg) {
            f32x4 acc = {0.f, 0.f, 0.f, 0.f};
            acc = __builtin_amdgcn_mfma_f32_16x16x32_bf16(afr[0], bfr[cg * 2 + 0], acc, 0, 0, 0);
            acc = __builtin_amdgcn_mfma_f32_16x16x32_bf16(afr[1], bfr[cg * 2 + 1], acc, 0, 0, 0);
            #pragma unroll
            for (int reg = 0; reg < 4; ++reg) {
                int rr = rbase + lg * 4 + reg;
                xws[(size_t)rr * 64 + cg * 16 + li] = f2bf(acc[reg] * dv[reg]);
            }
        }
    }
}

// ---------------------------------------------------------------------------
// pull aggregation: TWO nodes per wave, interleaved 8+8 gather groups,
// register accumulation, leakyReLU + residual fused.
// FINAL=1 (last layer): also computes out = X + x1/2 + x2/3 + xn3/4 (f32)
// and skips the bf16 x3 write entirely.
// ---------------------------------------------------------------------------
template<int XF32, int FINAL>
__global__ __launch_bounds__(256) void agg_kernel(
        const ushort_t* __restrict__ xws,
        const int2* __restrict__ rowinfo,
        const int* __restrict__ csr,
        const float* __restrict__ dinv,
        const float* __restrict__ bias,
        const float* __restrict__ xinf,    // f32 input (layer 0)
        const ushort_t* __restrict__ xinh, // bf16 input (layers >0)
        ushort_t* __restrict__ xout,       // bf16 layer output (FINAL=0)
        const float* __restrict__ Xres,    // X (FINAL=1)
        const ushort_t* __restrict__ x1res,// x1 (FINAL=1)
        float* __restrict__ outf,          // final f32 out (FINAL=1)
        int n) {
    int tid = threadIdx.x;
    int c   = tid & 63;
    int w   = blockIdx.x * 4 + (tid >> 6);
    int v0  = w * 2;
    if (v0 >= n) return;
    int  v1   = v0 + 1;
    bool has1 = (v1 < n);
    int  v1c  = has1 ? v1 : v0;

    int2 ri0 = rowinfo[v0];
    int2 ri1 = rowinfo[v1c];
    int b0 = ri0.x, len0 = ri0.y;
    int b1 = ri1.x, len1 = has1 ? ri1.y : 0;

    size_t vo0 = (size_t)v0  * 64 + c;
    size_t vo1 = (size_t)v1c * 64 + c;
    float acc0 = bf2f(xws[vo0]);     // self term (pre-scaled by dinv)
    float acc1 = bf2f(xws[vo1]);

    int mxlen = len0 > len1 ? len0 : len1;
    for (int off = 0; off < mxlen; off += 64) {
        int r0 = len0 - off;
        int r1 = len1 - off;
        int ce0 = (c < r0) ? csr[b0 + off + c] : n;
        int ce1 = (c < r1) ? csr[b1 + off + c] : n;
        int m0 = r0 < 64 ? r0 : 64;           // multiple of 8 (or <=0)
        int m1 = r1 < 64 ? r1 : 64;
        int mx = m0 > m1 ? m0 : m1;
        for (int j0 = 0; j0 < mx; j0 += 8) {
            float g0[8], g1[8];
            bool p0 = j0 < m0, p1 = j0 < m1;
            if (p0) {
                #pragma unroll
                for (int j = 0; j < 8; ++j) {
                    int s = __builtin_amdgcn_readlane(ce0, j0 + j);
                    g0[j] = bf2f(xws[(size_t)(unsigned)s * 64 + c]);
                }
            }
            if (p1) {
                #pragma unroll
                for (int j = 0; j < 8; ++j) {
                    int s = __builtin_amdgcn_readlane(ce1, j0 + j);
                    g1[j] = bf2f(xws[(size_t)(unsigned)s * 64 + c]);
                }
            }
            if (p0) {
                #pragma unroll
                for (int j = 0; j < 8; ++j) acc0 += g0[j];
            }
            if (p1) {
                #pragma unroll
                for (int j = 0; j < 8; ++j) acc1 += g1[j];
            }
        }
    }

    {
        float dv0 = dinv[v0];
        float t0  = bias[c] + dv0 * acc0;
        float a0  = t0 >= 0.f ? t0 : NEG_SLOPE * t0;
        float xi0 = XF32 ? xinf[vo0] : bf2f(xinh[vo0]);
        float xn0 = a0 + xi0;
        if (FINAL) {
            outf[vo0] = Xres[vo0] + 0.5f * bf2f(x1res[vo0])
                        + (1.f / 3.f) * xi0 + 0.25f * xn0;
        } else {
            xout[vo0] = f2bf(xn0);
        }
    }
    if (has1) {
        float dv1 = dinv[v1];
        float t1  = bias[c] + dv1 * acc1;
        float a1  = t1 >= 0.f ? t1 : NEG_SLOPE * t1;
        float xi1 = XF32 ? xinf[vo1] : bf2f(xinh[vo1]);
        float xn1 = a1 + xi1;
        if (FINAL) {
            outf[vo1] = Xres[vo1] + 0.5f * bf2f(x1res[vo1])
                        + (1.f / 3.f) * xi1 + 0.25f * xn1;
        } else {
            xout[vo1] = f2bf(xn1);
        }
    }
}

extern "C" void kernel_launch(void* const* d_in, const int* in_sizes, int n_in,
                              void* d_out, int out_size, void* d_ws, size_t ws_size,
                              hipStream_t stream) {
    const float* X   = (const float*)d_in[0];
    const int*   adj = (const int*)d_in[1];
    const float* W   = (const float*)d_in[2];
    const float* b   = (const float*)d_in[3];
    float* out = (float*)d_out;

    const int nd = in_sizes[0];          // N * 64
    const int n  = nd >> 6;              // N
    const int e  = in_sizes[1] / 2;      // E
    const int L  = in_sizes[3] / 64;     // layers (3)

    const int* src = adj;
    const int* dst = adj + e;

    const int nbk = (n + BSZ - 1) >> BSHIFT;             // ~196
    const int nch = (e + CHUNK - 1) / CHUNK;             // ~77
    const int M   = nbk * nch;                           // <= 16384
    const int csr_len = e + 8 * n + 64;

    // workspace layout
    unsigned* ebuf   = (unsigned*)d_ws;                  // e u32
    int*      csr    = (int*)(ebuf + e);                 // csr_len
    int*      m      = csr + csr_len;                    // 16384
    int*      galloc = m + 16384;                        // 4 (16B pad)
    ushort_t* wfrag  = (ushort_t*)(galloc + 4);          // 3 * 4096 bf16 (24KB)
    int2*     rowinfo= (int2*)(wfrag + 3 * 4096);        // n int2
    float*    dinv   = (float*)(rowinfo + n);            // n
    size_t    off    = ((size_t)(n + 3) & ~(size_t)3);
    ushort_t* xws    = (ushort_t*)(dinv + off);          // nd + 64
    ushort_t* x1     = xws + (size_t)nd + 64;            // nd
    ushort_t* x2     = x1  + (size_t)nd;                 // nd

    // ---- preprocessing (W-pack folded into hist's tail blocks) ----
    hist_kernel<<<nch + L, 1024, 0, stream>>>(dst, m, xws, W, wfrag, e, nbk, nch, n);
    scanm_kernel<<<1, 1024, 0, stream>>>(m, M, galloc);
    reorder_kernel<<<nch, 1024, 0, stream>>>(src, dst, m, ebuf, e, nbk, nch);
    fillmerge_kernel<<<nbk, 1024, 0, stream>>>(ebuf, m, galloc, rowinfo, dinv,
                                               csr, e, nbk, nch, n);

    // ---- layers ----
    int gemm_blocks = (n + 255) / 256;   // 4 waves x 64 rows per block
    int agg_blocks  = (n + 7) / 8;       // 2 nodes/wave, 4 waves/block
    // layer 0 (f32 X in, bf16 x1 out)
    gemm_mfma<1><<<gemm_blocks, 256, 0, stream>>>(X, nullptr, wfrag, dinv, xws, n);
    agg_kernel<1, 0><<<agg_blocks, 256, 0, stream>>>(xws, rowinfo, csr, dinv, b,
                                                     X, nullptr, x1,
                                                     nullptr, nullptr, nullptr, n);
    // layer 1
    gemm_mfma<0><<<gemm_blocks, 256, 0, stream>>>(nullptr, x1, wfrag + 4096, dinv, xws, n);
    agg_kernel<0, 0><<<agg_blocks, 256, 0, stream>>>(xws, rowinfo, csr, dinv, b + 64,
                                                     nullptr, x1, x2,
                                                     nullptr, nullptr, nullptr, n);
    // layer 2 (fused final: out = X + x1/2 + x2/3 + xn3/4)
    gemm_mfma<0><<<gemm_blocks, 256, 0, stream>>>(nullptr, x2, wfrag + 8192, dinv, xws, n);
    agg_kernel<0, 1><<<agg_blocks, 256, 0, stream>>>(xws, rowinfo, csr, dinv, b + 128,
                                                     nullptr, x2, nullptr,
                                                     X, x1, out, n);
}